// Round 1
// baseline (2391.656 us; speedup 1.0000x reference)
//
#include <hip/hip_runtime.h>

// ---------------- problem constants ----------------
#define V_SZ 32000
#define D_SZ 512
#define S_SZ 1024
#define H_SZ 2048
#define B_SZ 32
#define BS_SZ (B_SZ * S_SZ)   // 32768 rows
#define H_STEP 0.1f

typedef __attribute__((ext_vector_type(4))) float f32x4;
typedef __attribute__((ext_vector_type(8))) short s16x8;
typedef __attribute__((ext_vector_type(4))) unsigned short u16x4;
typedef unsigned short ushort_t;

__device__ __forceinline__ ushort_t f2b(float f) {
    unsigned u = __float_as_uint(f);
    unsigned r = (u + 0x7FFFu + ((u >> 16) & 1u)) >> 16;
    return (ushort_t)r;
}
__device__ __forceinline__ float b2f(ushort_t b) {
    return __uint_as_float(((unsigned)b) << 16);
}

__device__ __forceinline__ void gload_lds16(const void* g, void* l) {
    __builtin_amdgcn_global_load_lds(
        (const __attribute__((address_space(1))) unsigned int*)g,
        (__attribute__((address_space(3))) unsigned int*)l, 16, 0, 0);
}

// ---------------- prep kernels ----------------
__global__ void prep_w1(const float* __restrict__ W1,
                        ushort_t* __restrict__ W1b,
                        ushort_t* __restrict__ W1T) {
    int idx = blockIdx.x * 256 + threadIdx.x;   // over H*D = 1M
    float v = W1[idx];
    ushort_t b = f2b(v);
    int h = idx >> 9;          // / 512
    int d = idx & 511;
    W1b[idx] = b;
    W1T[(size_t)d * H_SZ + h] = b;
}

__global__ void prep_mass(const float* __restrict__ logm,
                          float* __restrict__ inv_mass,
                          float* __restrict__ mass) {
    int s = blockIdx.x * 256 + threadIdx.x;
    if (s < S_SZ) {
        float lm = logm[s];
        mass[s] = expf(lm);
        inv_mass[s] = expf(-lm);
    }
}

// ---------------- embedding + p0 ----------------
// one block per (b,s) row; 128 threads * 4 floats = 512 = D
__global__ void embed_kernel(const float* __restrict__ table,
                             const int* __restrict__ ids,
                             const float* __restrict__ mass,
                             float* __restrict__ q,
                             float* __restrict__ p,
                             ushort_t* __restrict__ qb) {
    int i = blockIdx.x;          // row index in [0, BS)
    int t = threadIdx.x;
    int s = i & (S_SZ - 1);
    int id = ids[i];
    int idp = (s == 0) ? id : ids[i - 1];   // s==0: prev = self -> vel 0
    float mk = (id != 0) ? 1.f : 0.f;
    float ms = mass[s];
    int d0 = t * 4;

    f32x4 cur = {0.f, 0.f, 0.f, 0.f};
    f32x4 prv = {0.f, 0.f, 0.f, 0.f};
    if (id != 0)  cur = *(const f32x4*)(table + (size_t)id  * D_SZ + d0);
    if (idp != 0) prv = *(const f32x4*)(table + (size_t)idp * D_SZ + d0);

    size_t off = (size_t)i * D_SZ + d0;
    *(f32x4*)(q + off) = cur;
    u16x4 cb;
    cb[0] = f2b(cur[0]); cb[1] = f2b(cur[1]); cb[2] = f2b(cur[2]); cb[3] = f2b(cur[3]);
    *(u16x4*)(qb + off) = cb;

    f32x4 pv;
    pv[0] = ms * (cur[0] - prv[0]) * mk;
    pv[1] = ms * (cur[1] - prv[1]) * mk;
    pv[2] = ms * (cur[2] - prv[2]) * mk;
    pv[3] = ms * (cur[3] - prv[3]) * mk;
    *(f32x4*)(p + off) = pv;
}

// ---------------- GEMM 1: U = epi(q @ W1^T) ----------------
// NT GEMM: C[i,h] = sum_k A[i,k]*B[h,k];  A=q_bf16 [BS,512], B=W1b [2048,512]
// epilogue: U[i,h] = bf16((1 - tanh^2(C + b1[h])) * w2[h])
__global__ __launch_bounds__(256) void gemm_force1(
        const ushort_t* __restrict__ Abf,
        const ushort_t* __restrict__ Bbf,
        const float* __restrict__ b1,
        const float* __restrict__ W2,
        ushort_t* __restrict__ U) {
    const int K = D_SZ;   // 512
    __shared__ __align__(16) ushort_t lA[2][128 * 64];
    __shared__ __align__(16) ushort_t lB[2][128 * 64];

    int tid = threadIdx.x;
    int w = tid >> 6, lane = tid & 63;
    int wr = w >> 1, wc = w & 1;
    int lr = lane & 15, lk = lane >> 4;
    long rowA = (long)blockIdx.x * 128;
    long rowB = (long)blockIdx.y * 128;

    f32x4 acc[4][4];
    #pragma unroll
    for (int m = 0; m < 4; ++m)
        #pragma unroll
        for (int n = 0; n < 4; ++n)
            acc[m][n] = (f32x4){0.f, 0.f, 0.f, 0.f};

    auto stage = [&](int buf, int kt) {
        int k0 = kt * 64;
        #pragma unroll
        for (int ld = 0; ld < 4; ++ld) {
            int c = (ld * 4 + w) * 64 + lane;   // 0..1023 chunk of 16B
            int r = c >> 3, kc = c & 7;
            gload_lds16(Abf + (rowA + r) * (long)K + k0 + kc * 8, &lA[buf][c * 8]);
            gload_lds16(Bbf + (rowB + r) * (long)K + k0 + kc * 8, &lB[buf][c * 8]);
        }
    };

    stage(0, 0);
    __syncthreads();
    const int NT = K / 64;
    for (int kt = 0; kt < NT; ++kt) {
        int buf = kt & 1;
        if (kt + 1 < NT) stage(buf ^ 1, kt + 1);
        #pragma unroll
        for (int kk = 0; kk < 2; ++kk) {
            s16x8 av[4], bv[4];
            #pragma unroll
            for (int m = 0; m < 4; ++m)
                av[m] = *(const s16x8*)&lA[buf][(wr * 64 + m * 16 + lr) * 64 + kk * 32 + lk * 8];
            #pragma unroll
            for (int n = 0; n < 4; ++n)
                bv[n] = *(const s16x8*)&lB[buf][(wc * 64 + n * 16 + lr) * 64 + kk * 32 + lk * 8];
            #pragma unroll
            for (int m = 0; m < 4; ++m)
                #pragma unroll
                for (int n = 0; n < 4; ++n)
                    acc[m][n] = __builtin_amdgcn_mfma_f32_16x16x32_bf16(av[m], bv[n], acc[m][n], 0, 0, 0);
        }
        __syncthreads();
    }

    float b1h[4], w2h[4];
    #pragma unroll
    for (int n = 0; n < 4; ++n) {
        int h = (int)rowB + wc * 64 + n * 16 + lr;
        b1h[n] = b1[h];
        w2h[n] = W2[h];
    }
    #pragma unroll
    for (int m = 0; m < 4; ++m) {
        #pragma unroll
        for (int j = 0; j < 4; ++j) {
            long i = rowA + wr * 64 + m * 16 + lk * 4 + j;
            #pragma unroll
            for (int n = 0; n < 4; ++n) {
                int h = (int)rowB + wc * 64 + n * 16 + lr;
                float uu = acc[m][n][j] + b1h[n];
                float t = tanhf(uu);
                U[i * H_SZ + h] = f2b((1.f - t * t) * w2h[n]);
            }
        }
    }
}

// ---------------- GEMM 2: G = U @ W1, fused leapfrog update ----------------
// NT GEMM: G[i,d] = sum_h U[i,h] * W1T[d,h];  A=U [BS,2048], B=W1T [512,2048]
// epilogue: p[i,d] -= coef*mask*G ; if(do_q) q += 0.1*p*inv_mass*mask ; qb=bf16(q)
__global__ __launch_bounds__(256) void gemm_force2(
        const ushort_t* __restrict__ U,
        const ushort_t* __restrict__ W1T,
        const int* __restrict__ ids,
        const float* __restrict__ inv_mass,
        float* __restrict__ q,
        float* __restrict__ p,
        ushort_t* __restrict__ qb,
        float coef, int do_q) {
    const int K = H_SZ;   // 2048
    __shared__ __align__(16) ushort_t lA[2][128 * 64];
    __shared__ __align__(16) ushort_t lB[2][128 * 64];

    int tid = threadIdx.x;
    int w = tid >> 6, lane = tid & 63;
    int wr = w >> 1, wc = w & 1;
    int lr = lane & 15, lk = lane >> 4;
    long rowA = (long)blockIdx.x * 128;
    long rowB = (long)blockIdx.y * 128;   // d-block base (N=512)

    f32x4 acc[4][4];
    #pragma unroll
    for (int m = 0; m < 4; ++m)
        #pragma unroll
        for (int n = 0; n < 4; ++n)
            acc[m][n] = (f32x4){0.f, 0.f, 0.f, 0.f};

    auto stage = [&](int buf, int kt) {
        int k0 = kt * 64;
        #pragma unroll
        for (int ld = 0; ld < 4; ++ld) {
            int c = (ld * 4 + w) * 64 + lane;
            int r = c >> 3, kc = c & 7;
            gload_lds16(U + (rowA + r) * (long)K + k0 + kc * 8, &lA[buf][c * 8]);
            gload_lds16(W1T + (rowB + r) * (long)K + k0 + kc * 8, &lB[buf][c * 8]);
        }
    };

    stage(0, 0);
    __syncthreads();
    const int NT = K / 64;
    for (int kt = 0; kt < NT; ++kt) {
        int buf = kt & 1;
        if (kt + 1 < NT) stage(buf ^ 1, kt + 1);
        #pragma unroll
        for (int kk = 0; kk < 2; ++kk) {
            s16x8 av[4], bv[4];
            #pragma unroll
            for (int m = 0; m < 4; ++m)
                av[m] = *(const s16x8*)&lA[buf][(wr * 64 + m * 16 + lr) * 64 + kk * 32 + lk * 8];
            #pragma unroll
            for (int n = 0; n < 4; ++n)
                bv[n] = *(const s16x8*)&lB[buf][(wc * 64 + n * 16 + lr) * 64 + kk * 32 + lk * 8];
            #pragma unroll
            for (int m = 0; m < 4; ++m)
                #pragma unroll
                for (int n = 0; n < 4; ++n)
                    acc[m][n] = __builtin_amdgcn_mfma_f32_16x16x32_bf16(av[m], bv[n], acc[m][n], 0, 0, 0);
        }
        __syncthreads();
    }

    #pragma unroll
    for (int m = 0; m < 4; ++m) {
        #pragma unroll
        for (int j = 0; j < 4; ++j) {
            long i = rowA + wr * 64 + m * 16 + lk * 4 + j;
            int id = ids[i];
            float mask = (id != 0) ? 1.f : 0.f;
            float im = inv_mass[(int)(i & (S_SZ - 1))];
            #pragma unroll
            for (int n = 0; n < 4; ++n) {
                int d = (int)rowB + wc * 64 + n * 16 + lr;
                size_t off = (size_t)i * D_SZ + d;
                float pn = p[off] - coef * mask * acc[m][n][j];
                p[off] = pn;
                if (do_q) {
                    float qn = q[off] + H_STEP * pn * im * mask;
                    q[off] = qn;
                    qb[off] = f2b(qn);
                }
            }
        }
    }
}

// ---------------- host launch ----------------
extern "C" void kernel_launch(void* const* d_in, const int* in_sizes, int n_in,
                              void* d_out, int out_size, void* d_ws, size_t ws_size,
                              hipStream_t stream) {
    const float* table = (const float*)d_in[0];
    const float* logm  = (const float*)d_in[1];
    const float* W1    = (const float*)d_in[2];
    const float* b1    = (const float*)d_in[3];
    const float* W2    = (const float*)d_in[4];
    // d_in[5] = b2, unused by the force (only shifts the potential value)
    const int*   ids   = (const int*)d_in[6];

    float* q = (float*)d_out;                       // [BS, D]
    float* p = q + (size_t)BS_SZ * D_SZ;            // [BS, D]

    char* ws = (char*)d_ws;
    size_t o = 0;
    ushort_t* qb  = (ushort_t*)(ws + o); o += (size_t)BS_SZ * D_SZ * 2;   // 32 MB
    ushort_t* U   = (ushort_t*)(ws + o); o += (size_t)BS_SZ * H_SZ * 2;   // 128 MB
    ushort_t* W1b = (ushort_t*)(ws + o); o += (size_t)H_SZ * D_SZ * 2;    // 2 MB
    ushort_t* W1T = (ushort_t*)(ws + o); o += (size_t)D_SZ * H_SZ * 2;    // 2 MB
    float* inv_mass = (float*)(ws + o);  o += S_SZ * 4;
    float* mass     = (float*)(ws + o);  o += S_SZ * 4;

    prep_w1<<<(H_SZ * D_SZ) / 256, 256, 0, stream>>>(W1, W1b, W1T);
    prep_mass<<<(S_SZ + 255) / 256, 256, 0, stream>>>(logm, inv_mass, mass);
    embed_kernel<<<BS_SZ, 128, 0, stream>>>(table, ids, mass, q, p, qb);

    // 6 distinct force evals: j=0 -> +0.05*f(q0); j=1..4 -> +0.1*f(qj); j=5 -> +0.05*f(q5)
    for (int j = 0; j < 6; ++j) {
        gemm_force1<<<dim3(BS_SZ / 128, H_SZ / 128), 256, 0, stream>>>(qb, W1b, b1, W2, U);
        float coef = (j == 0 || j == 5) ? 0.05f : 0.1f;
        gemm_force2<<<dim3(BS_SZ / 128, D_SZ / 128), 256, 0, stream>>>(
            U, W1T, ids, inv_mass, q, p, qb, coef, (j < 5) ? 1 : 0);
    }
}

// Round 2
// 1900.689 us; speedup vs baseline: 1.2583x; 1.2583x over previous
//
#include <hip/hip_runtime.h>

// ---------------- problem constants ----------------
#define V_SZ 32000
#define D_SZ 512
#define S_SZ 1024
#define H_SZ 2048
#define B_SZ 32
#define BS_SZ (B_SZ * S_SZ)   // 32768 rows
#define H_STEP 0.1f

typedef __attribute__((ext_vector_type(4))) float f32x4;
typedef __attribute__((ext_vector_type(8))) short s16x8;
typedef __attribute__((ext_vector_type(4))) unsigned short u16x4;
typedef unsigned short ushort_t;

__device__ __forceinline__ ushort_t f2b(float f) {
    unsigned u = __float_as_uint(f);
    unsigned r = (u + 0x7FFFu + ((u >> 16) & 1u)) >> 16;
    return (ushort_t)r;
}

__device__ __forceinline__ void gload_lds16(const void* g, void* l) {
    __builtin_amdgcn_global_load_lds(
        (const __attribute__((address_space(1))) unsigned int*)g,
        (__attribute__((address_space(3))) unsigned int*)l, 16, 0, 0);
}

// ---------------- prep kernels ----------------
__global__ void prep_w1(const float* __restrict__ W1,
                        ushort_t* __restrict__ W1b,
                        ushort_t* __restrict__ W1T) {
    int idx = blockIdx.x * 256 + threadIdx.x;   // over H*D = 1M
    float v = W1[idx];
    ushort_t b = f2b(v);
    int h = idx >> 9;          // / 512
    int d = idx & 511;
    W1b[idx] = b;
    W1T[(size_t)d * H_SZ + h] = b;
}

__global__ void prep_mass(const float* __restrict__ logm,
                          float* __restrict__ inv_mass,
                          float* __restrict__ mass) {
    int s = blockIdx.x * 256 + threadIdx.x;
    if (s < S_SZ) {
        float lm = logm[s];
        mass[s] = expf(lm);
        inv_mass[s] = expf(-lm);
    }
}

// ---------------- embedding + p0 ----------------
__global__ void embed_kernel(const float* __restrict__ table,
                             const int* __restrict__ ids,
                             const float* __restrict__ mass,
                             float* __restrict__ q,
                             float* __restrict__ p,
                             ushort_t* __restrict__ qb) {
    int i = blockIdx.x;          // row index in [0, BS)
    int t = threadIdx.x;
    int s = i & (S_SZ - 1);
    int id = ids[i];
    int idp = (s == 0) ? id : ids[i - 1];   // s==0: prev = self -> vel 0
    float mk = (id != 0) ? 1.f : 0.f;
    float ms = mass[s];
    int d0 = t * 4;

    f32x4 cur = {0.f, 0.f, 0.f, 0.f};
    f32x4 prv = {0.f, 0.f, 0.f, 0.f};
    if (id != 0)  cur = *(const f32x4*)(table + (size_t)id  * D_SZ + d0);
    if (idp != 0) prv = *(const f32x4*)(table + (size_t)idp * D_SZ + d0);

    size_t off = (size_t)i * D_SZ + d0;
    *(f32x4*)(q + off) = cur;
    u16x4 cb;
    cb[0] = f2b(cur[0]); cb[1] = f2b(cur[1]); cb[2] = f2b(cur[2]); cb[3] = f2b(cur[3]);
    *(u16x4*)(qb + off) = cb;

    f32x4 pv;
    pv[0] = ms * (cur[0] - prv[0]) * mk;
    pv[1] = ms * (cur[1] - prv[1]) * mk;
    pv[2] = ms * (cur[2] - prv[2]) * mk;
    pv[3] = ms * (cur[3] - prv[3]) * mk;
    *(f32x4*)(p + off) = pv;
}

// ---------------- GEMM 1: U[i,h] = sech2(qW1^T + b1)*w2 ----------------
// Swapped operands: A = W1b (rows h, K=512), B = qb (rows i, K=512)
// C[r=h][c=i]; per-thread regs = 4 consecutive h -> u16x4 stores to U[i,h].
__global__ __launch_bounds__(256) void gemm_force1(
        const ushort_t* __restrict__ Abf,   // W1b [H,512]
        const ushort_t* __restrict__ Bbf,   // qb  [BS,512]
        const float* __restrict__ b1,
        const float* __restrict__ W2,
        ushort_t* __restrict__ U) {
    const int K = D_SZ;   // 512
    __shared__ __align__(16) ushort_t lA[2][128 * 64];
    __shared__ __align__(16) ushort_t lB[2][128 * 64];

    int tid = threadIdx.x;
    int w = tid >> 6, lane = tid & 63;
    int wr = w >> 1, wc = w & 1;
    int lr = lane & 15, lk = lane >> 4;

    // bijective XCD swizzle: nwg = 4096, 16 x-blocks (h) share one qb i-tile
    int bid = blockIdx.x;
    int wgid = (bid & 7) * (4096 >> 3) + (bid >> 3);
    int bx = wgid & 15;          // h-block  (16)
    int by = wgid >> 4;          // i-block  (256)
    long rowA = (long)bx * 128;  // h base
    long rowB = (long)by * 128;  // i base

    f32x4 acc[4][4];
    #pragma unroll
    for (int m = 0; m < 4; ++m)
        #pragma unroll
        for (int n = 0; n < 4; ++n)
            acc[m][n] = (f32x4){0.f, 0.f, 0.f, 0.f};

    auto stage = [&](int buf, int kt) {
        int k0 = kt * 64;
        #pragma unroll
        for (int ld = 0; ld < 4; ++ld) {
            int c = (ld * 4 + w) * 64 + lane;   // 0..1023 chunk of 16B
            int r = c >> 3, kc = c & 7;
            gload_lds16(Abf + (rowA + r) * (long)K + k0 + kc * 8, &lA[buf][c * 8]);
            gload_lds16(Bbf + (rowB + r) * (long)K + k0 + kc * 8, &lB[buf][c * 8]);
        }
    };

    stage(0, 0);
    __syncthreads();
    const int NT = K / 64;
    for (int kt = 0; kt < NT; ++kt) {
        int buf = kt & 1;
        if (kt + 1 < NT) stage(buf ^ 1, kt + 1);
        #pragma unroll
        for (int kk = 0; kk < 2; ++kk) {
            s16x8 av[4], bv[4];
            #pragma unroll
            for (int m = 0; m < 4; ++m)
                av[m] = *(const s16x8*)&lA[buf][(wr * 64 + m * 16 + lr) * 64 + kk * 32 + lk * 8];
            #pragma unroll
            for (int n = 0; n < 4; ++n)
                bv[n] = *(const s16x8*)&lB[buf][(wc * 64 + n * 16 + lr) * 64 + kk * 32 + lk * 8];
            #pragma unroll
            for (int m = 0; m < 4; ++m)
                #pragma unroll
                for (int n = 0; n < 4; ++n)
                    acc[m][n] = __builtin_amdgcn_mfma_f32_16x16x32_bf16(av[m], bv[n], acc[m][n], 0, 0, 0);
        }
        __syncthreads();
    }

    #pragma unroll
    for (int m = 0; m < 4; ++m) {
        int h0 = (int)rowA + wr * 64 + m * 16 + lk * 4;
        f32x4 b1v = *(const f32x4*)(b1 + h0);
        f32x4 w2v = *(const f32x4*)(W2 + h0);
        #pragma unroll
        for (int n = 0; n < 4; ++n) {
            long i = rowB + wc * 64 + n * 16 + lr;
            u16x4 ub;
            #pragma unroll
            for (int j = 0; j < 4; ++j) {
                float uu = acc[m][n][j] + b1v[j];
                // sech^2(u) = 4e/(1+e)^2, e = exp(-2|u|)  (branch-free, no overflow)
                float e = __expf(-2.0f * fabsf(uu));
                float r = 1.0f / (1.0f + e);
                ub[j] = f2b(4.0f * e * r * r * w2v[j]);
            }
            *(u16x4*)(U + i * H_SZ + h0) = ub;
        }
    }
}

// ---------------- GEMM 2: G = U @ W1, fused leapfrog update ----------------
// Swapped operands: A = W1T (rows d, K=2048), B = U (rows i, K=2048)
// C[r=d][c=i]; per-thread regs = 4 consecutive d -> f32x4 p/q updates.
__global__ __launch_bounds__(256) void gemm_force2(
        const ushort_t* __restrict__ W1T,   // [512, 2048]
        const ushort_t* __restrict__ U,     // [BS, 2048]
        const int* __restrict__ ids,
        const float* __restrict__ inv_mass,
        float* __restrict__ q,
        float* __restrict__ p,
        ushort_t* __restrict__ qb,
        float coef, int do_q) {
    const int K = H_SZ;   // 2048
    __shared__ __align__(16) ushort_t lA[2][128 * 64];
    __shared__ __align__(16) ushort_t lB[2][128 * 64];

    int tid = threadIdx.x;
    int w = tid >> 6, lane = tid & 63;
    int wr = w >> 1, wc = w & 1;
    int lr = lane & 15, lk = lane >> 4;

    // bijective XCD swizzle: nwg = 1024, 4 x-blocks (d) share one U i-tile
    int bid = blockIdx.x;
    int wgid = (bid & 7) * (1024 >> 3) + (bid >> 3);
    int bx = wgid & 3;           // d-block (4)
    int by = wgid >> 2;          // i-block (256)
    long rowA = (long)bx * 128;  // d base
    long rowB = (long)by * 128;  // i base

    f32x4 acc[4][4];
    #pragma unroll
    for (int m = 0; m < 4; ++m)
        #pragma unroll
        for (int n = 0; n < 4; ++n)
            acc[m][n] = (f32x4){0.f, 0.f, 0.f, 0.f};

    auto stage = [&](int buf, int kt) {
        int k0 = kt * 64;
        #pragma unroll
        for (int ld = 0; ld < 4; ++ld) {
            int c = (ld * 4 + w) * 64 + lane;
            int r = c >> 3, kc = c & 7;
            gload_lds16(W1T + (rowA + r) * (long)K + k0 + kc * 8, &lA[buf][c * 8]);
            gload_lds16(U   + (rowB + r) * (long)K + k0 + kc * 8, &lB[buf][c * 8]);
        }
    };

    stage(0, 0);
    __syncthreads();
    const int NT = K / 64;
    for (int kt = 0; kt < NT; ++kt) {
        int buf = kt & 1;
        if (kt + 1 < NT) stage(buf ^ 1, kt + 1);
        #pragma unroll
        for (int kk = 0; kk < 2; ++kk) {
            s16x8 av[4], bv[4];
            #pragma unroll
            for (int m = 0; m < 4; ++m)
                av[m] = *(const s16x8*)&lA[buf][(wr * 64 + m * 16 + lr) * 64 + kk * 32 + lk * 8];
            #pragma unroll
            for (int n = 0; n < 4; ++n)
                bv[n] = *(const s16x8*)&lB[buf][(wc * 64 + n * 16 + lr) * 64 + kk * 32 + lk * 8];
            #pragma unroll
            for (int m = 0; m < 4; ++m)
                #pragma unroll
                for (int n = 0; n < 4; ++n)
                    acc[m][n] = __builtin_amdgcn_mfma_f32_16x16x32_bf16(av[m], bv[n], acc[m][n], 0, 0, 0);
        }
        __syncthreads();
    }

    #pragma unroll
    for (int n = 0; n < 4; ++n) {
        long i = rowB + wc * 64 + n * 16 + lr;
        int id = ids[i];
        float cm = (id != 0) ? coef : 0.f;         // coef * mask
        float hm = (id != 0) ? H_STEP : 0.f;       // H_STEP * mask
        float im = inv_mass[(int)(i & (S_SZ - 1))];
        #pragma unroll
        for (int m = 0; m < 4; ++m) {
            int d0 = (int)rowA + wr * 64 + m * 16 + lk * 4;
            size_t off = (size_t)i * D_SZ + d0;
            f32x4 pv = *(const f32x4*)(p + off);
            #pragma unroll
            for (int j = 0; j < 4; ++j)
                pv[j] -= cm * acc[m][n][j];
            *(f32x4*)(p + off) = pv;
            if (do_q) {
                f32x4 qv = *(const f32x4*)(q + off);
                u16x4 qbv;
                #pragma unroll
                for (int j = 0; j < 4; ++j) {
                    qv[j] += hm * pv[j] * im;
                    qbv[j] = f2b(qv[j]);
                }
                *(f32x4*)(q + off) = qv;
                *(u16x4*)(qb + off) = qbv;
            }
        }
    }
}

// ---------------- host launch ----------------
extern "C" void kernel_launch(void* const* d_in, const int* in_sizes, int n_in,
                              void* d_out, int out_size, void* d_ws, size_t ws_size,
                              hipStream_t stream) {
    const float* table = (const float*)d_in[0];
    const float* logm  = (const float*)d_in[1];
    const float* W1    = (const float*)d_in[2];
    const float* b1    = (const float*)d_in[3];
    const float* W2    = (const float*)d_in[4];
    // d_in[5] = b2, unused by the force (only shifts the potential value)
    const int*   ids   = (const int*)d_in[6];

    float* q = (float*)d_out;                       // [BS, D]
    float* p = q + (size_t)BS_SZ * D_SZ;            // [BS, D]

    char* ws = (char*)d_ws;
    size_t o = 0;
    ushort_t* qb  = (ushort_t*)(ws + o); o += (size_t)BS_SZ * D_SZ * 2;   // 32 MB
    ushort_t* U   = (ushort_t*)(ws + o); o += (size_t)BS_SZ * H_SZ * 2;   // 128 MB
    ushort_t* W1b = (ushort_t*)(ws + o); o += (size_t)H_SZ * D_SZ * 2;    // 2 MB
    ushort_t* W1T = (ushort_t*)(ws + o); o += (size_t)D_SZ * H_SZ * 2;    // 2 MB
    float* inv_mass = (float*)(ws + o);  o += S_SZ * 4;
    float* mass     = (float*)(ws + o);  o += S_SZ * 4;

    prep_w1<<<(H_SZ * D_SZ) / 256, 256, 0, stream>>>(W1, W1b, W1T);
    prep_mass<<<(S_SZ + 255) / 256, 256, 0, stream>>>(logm, inv_mass, mass);
    embed_kernel<<<BS_SZ, 128, 0, stream>>>(table, ids, mass, q, p, qb);

    // 6 distinct force evals: j=0 -> +0.05*f(q0); j=1..4 -> +0.1*f(qj); j=5 -> +0.05*f(q5)
    for (int j = 0; j < 6; ++j) {
        gemm_force1<<<4096, 256, 0, stream>>>(W1b, qb, b1, W2, U);
        float coef = (j == 0 || j == 5) ? 0.05f : 0.1f;
        gemm_force2<<<1024, 256, 0, stream>>>(
            W1T, U, ids, inv_mass, q, p, qb, coef, (j < 5) ? 1 : 0);
    }
}

// Round 3
// 1432.129 us; speedup vs baseline: 1.6700x; 1.3272x over previous
//
#include <hip/hip_runtime.h>

// ---------------- problem constants ----------------
#define D_SZ 512
#define S_SZ 1024
#define H_SZ 2048
#define BS_SZ 32768
#define H_STEP 0.1f

typedef __attribute__((ext_vector_type(4))) float f32x4;
typedef __attribute__((ext_vector_type(8))) short s16x8;
typedef __attribute__((ext_vector_type(4))) unsigned short u16x4;
typedef unsigned short ushort_t;

__device__ __forceinline__ ushort_t f2b(float f) {
    unsigned u = __float_as_uint(f);
    unsigned r = (u + 0x7FFFu + ((u >> 16) & 1u)) >> 16;
    return (ushort_t)r;
}

__device__ __forceinline__ void gload_lds16(const void* g, void* l) {
    __builtin_amdgcn_global_load_lds(
        (const __attribute__((address_space(1))) unsigned int*)g,
        (__attribute__((address_space(3))) unsigned int*)l, 16, 0, 0);
}

// ---------------- prep kernels ----------------
__global__ void prep_w1(const float* __restrict__ W1,
                        ushort_t* __restrict__ W1b,
                        ushort_t* __restrict__ W1T) {
    int idx = blockIdx.x * 256 + threadIdx.x;   // over H*D = 1M
    float v = W1[idx];
    ushort_t b = f2b(v);
    int h = idx >> 9;          // / 512
    int d = idx & 511;
    W1b[idx] = b;
    W1T[(size_t)d * H_SZ + h] = b;
}

__global__ void prep_mass(const float* __restrict__ logm,
                          float* __restrict__ inv_mass,
                          float* __restrict__ mass) {
    int s = blockIdx.x * 256 + threadIdx.x;
    if (s < S_SZ) {
        float lm = logm[s];
        mass[s] = expf(lm);
        inv_mass[s] = expf(-lm);
    }
}

// ---------------- embedding + p0 ----------------
__global__ void embed_kernel(const float* __restrict__ table,
                             const int* __restrict__ ids,
                             const float* __restrict__ mass,
                             float* __restrict__ q,
                             float* __restrict__ p,
                             ushort_t* __restrict__ qb) {
    int i = blockIdx.x;          // row index in [0, BS)
    int t = threadIdx.x;
    int s = i & (S_SZ - 1);
    int id = ids[i];
    int idp = (s == 0) ? id : ids[i - 1];   // s==0: prev = self -> vel 0
    float mk = (id != 0) ? 1.f : 0.f;
    float ms = mass[s];
    int d0 = t * 4;

    f32x4 cur = {0.f, 0.f, 0.f, 0.f};
    f32x4 prv = {0.f, 0.f, 0.f, 0.f};
    if (id != 0)  cur = *(const f32x4*)(table + (size_t)id  * D_SZ + d0);
    if (idp != 0) prv = *(const f32x4*)(table + (size_t)idp * D_SZ + d0);

    size_t off = (size_t)i * D_SZ + d0;
    *(f32x4*)(q + off) = cur;
    u16x4 cb;
    cb[0] = f2b(cur[0]); cb[1] = f2b(cur[1]); cb[2] = f2b(cur[2]); cb[3] = f2b(cur[3]);
    *(u16x4*)(qb + off) = cb;

    f32x4 pv;
    pv[0] = ms * (cur[0] - prv[0]) * mk;
    pv[1] = ms * (cur[1] - prv[1]) * mk;
    pv[2] = ms * (cur[2] - prv[2]) * mk;
    pv[3] = ms * (cur[3] - prv[3]) * mk;
    *(f32x4*)(p + off) = pv;
}

// =====================================================================
// Phased 256x256 GEMM core, BK=32, 3 LDS buffers, counted vmcnt(4),
// T2 XOR-swizzle (pre-swizzled global source, swizzled ds_read),
// T5 setprio around MFMA clusters, bijective XCD swizzle.
// C[r][c] = sum_k A[r,k]*B[c,k];  A rows = MAB*256, B rows = 32768.
// EPI 0: force1 (U store); EPI 1: force2 (p/q leapfrog update).
// =====================================================================
template<int KLEN, int MAB, int EPI>
__global__ __launch_bounds__(512, 2) void gemm8(
        const ushort_t* __restrict__ A,
        const ushort_t* __restrict__ B,
        const float* __restrict__ b1,
        const float* __restrict__ W2,
        ushort_t* __restrict__ U,
        const int* __restrict__ ids,
        const float* __restrict__ inv_mass,
        float* __restrict__ q,
        float* __restrict__ p,
        ushort_t* __restrict__ qb,
        float coef, int do_q) {
    constexpr int NT = KLEN / 32;
    __shared__ __align__(16) ushort_t lA[3][256 * 32];
    __shared__ __align__(16) ushort_t lB[3][256 * 32];

    const int tid = threadIdx.x;
    const int lane = tid & 63, wid = tid >> 6;
    const int wm = wid >> 2, wn = wid & 3;           // 2 x 4 wave grid
    const int lr = lane & 15, lk = lane >> 4;

    // bijective XCD swizzle (nwg % 8 == 0); small dim (A-blocks) fastest
    const int nwg = MAB * 128;
    int wgid = ((int)blockIdx.x & 7) * (nwg >> 3) + ((int)blockIdx.x >> 3);
    int bxA = wgid % MAB;
    int by  = wgid / MAB;
    const long a0 = (long)bxA * 256;
    const long b0 = (long)by * 256;

    // ---- staging precompute: thread stages chunks c=tid and c=tid+512 per array
    // chunk c -> row r=c>>2, 16B-slot kc=c&3; swizzled source slot kc^((r>>1)&3)
    const int r1  = tid >> 2;                 // 0..127 (second chunk: +128, same swz)
    const int kc  = tid & 3;
    const int kcs = kc ^ ((r1 >> 1) & 3);
    const ushort_t* gA1 = A + (a0 + r1) * (long)KLEN + kcs * 8;
    const ushort_t* gA2 = gA1 + (long)128 * KLEN;
    const ushort_t* gB1 = B + (b0 + r1) * (long)KLEN + kcs * 8;
    const ushort_t* gB2 = gB1 + (long)128 * KLEN;
    const int ld1 = tid * 8;
    const int ld2 = (tid + 512) * 8;

#define STAGE_A(t) { int _b = (t) % 3;                         \
    gload_lds16(gA1 + (long)(t) * 32, &lA[_b][ld1]);           \
    gload_lds16(gA2 + (long)(t) * 32, &lA[_b][ld2]); }
#define STAGE_B(t) { int _b = (t) % 3;                         \
    gload_lds16(gB1 + (long)(t) * 32, &lB[_b][ld1]);           \
    gload_lds16(gB2 + (long)(t) * 32, &lB[_b][ld2]); }

    f32x4 acc[8][4];
    #pragma unroll
    for (int m = 0; m < 8; ++m)
        #pragma unroll
        for (int n = 0; n < 4; ++n)
            acc[m][n] = (f32x4){0.f, 0.f, 0.f, 0.f};

    // ds_read fragment offsets (ushort units), swizzled slot lk^((lr>>1)&3)
    const int lks8 = (lk ^ ((lr >> 1) & 3)) * 8;
    const int roA = (wm * 128 + lr) * 32 + lks8;   // + m*512 per 16-row frag
    const int roB = (wn * 64 + lr) * 32 + lks8;    // + n*512

    // prologue: tiles 0 and 1 in flight (8 loads/thread)
    STAGE_A(0); STAGE_B(0);
    STAGE_A(1); STAGE_B(1);

    for (int t = 0; t < NT; ++t) {
        const int buf = t % 3;
        const ushort_t* bA = &lA[buf][0];
        const ushort_t* bB = &lB[buf][0];
        // tile start: require tile t staged (keep tile t+1's 4 loads in flight)
        asm volatile("s_waitcnt vmcnt(4)" ::: "memory");
        __builtin_amdgcn_s_barrier();

        // ---- phase 0: frags m0..3 (all n), stage A of tile t+2
        s16x8 av[4], bv[4];
        #pragma unroll
        for (int m = 0; m < 4; ++m) av[m] = *(const s16x8*)&bA[roA + m * 512];
        #pragma unroll
        for (int n = 0; n < 4; ++n) bv[n] = *(const s16x8*)&bB[roB + n * 512];
        if (t + 2 < NT) STAGE_A(t + 2);
        __builtin_amdgcn_s_setprio(1);
        #pragma unroll
        for (int m = 0; m < 4; ++m)
            #pragma unroll
            for (int n = 0; n < 4; ++n)
                acc[m][n] = __builtin_amdgcn_mfma_f32_16x16x32_bf16(av[m], bv[n], acc[m][n], 0, 0, 0);
        __builtin_amdgcn_s_setprio(0);
        __builtin_amdgcn_s_barrier();

        // ---- phase 1: frags m4..7 (bv held in regs), stage B of tile t+2
        s16x8 av2[4];
        #pragma unroll
        for (int m = 0; m < 4; ++m) av2[m] = *(const s16x8*)&bA[roA + (m + 4) * 512];
        if (t + 2 < NT) STAGE_B(t + 2);
        __builtin_amdgcn_s_setprio(1);
        #pragma unroll
        for (int m = 0; m < 4; ++m)
            #pragma unroll
            for (int n = 0; n < 4; ++n)
                acc[m + 4][n] = __builtin_amdgcn_mfma_f32_16x16x32_bf16(av2[m], bv[n], acc[m + 4][n], 0, 0, 0);
        __builtin_amdgcn_s_setprio(0);
    }
#undef STAGE_A
#undef STAGE_B

    if constexpr (EPI == 0) {
        // U[i,h] = bf16(sech2(C + b1[h]) * w2[h]); reg axis = h (contiguous)
        #pragma unroll
        for (int m = 0; m < 8; ++m) {
            long h0 = a0 + wm * 128 + m * 16 + lk * 4;
            f32x4 b1v = *(const f32x4*)(b1 + h0);
            f32x4 w2v = *(const f32x4*)(W2 + h0);
            #pragma unroll
            for (int n = 0; n < 4; ++n) {
                long i = b0 + wn * 64 + n * 16 + lr;
                u16x4 ub;
                #pragma unroll
                for (int j = 0; j < 4; ++j) {
                    float uu = acc[m][n][j] + b1v[j];
                    // sech^2(u) = 4e/(1+e)^2, e = exp(-2|u|)
                    float e = __expf(-2.0f * fabsf(uu));
                    float rr = 1.0f / (1.0f + e);
                    ub[j] = f2b(4.0f * e * rr * rr * w2v[j]);
                }
                *(u16x4*)(U + i * H_SZ + h0) = ub;
            }
        }
    } else {
        // p -= coef*mask*G ; q += 0.1*p/mass*mask ; qb = bf16(q). reg axis = d.
        #pragma unroll
        for (int n = 0; n < 4; ++n) {
            long i = b0 + wn * 64 + n * 16 + lr;
            int id = ids[i];
            float cm = (id != 0) ? coef : 0.f;
            float hm = (id != 0) ? H_STEP : 0.f;
            float im = inv_mass[(int)(i & (S_SZ - 1))];
            #pragma unroll
            for (int m = 0; m < 8; ++m) {
                long d0 = a0 + wm * 128 + m * 16 + lk * 4;
                size_t off = (size_t)i * D_SZ + d0;
                f32x4 pv = *(const f32x4*)(p + off);
                #pragma unroll
                for (int j = 0; j < 4; ++j)
                    pv[j] -= cm * acc[m][n][j];
                *(f32x4*)(p + off) = pv;
                if (do_q) {
                    f32x4 qv = *(const f32x4*)(q + off);
                    u16x4 qbv;
                    #pragma unroll
                    for (int j = 0; j < 4; ++j) {
                        qv[j] += hm * pv[j] * im;
                        qbv[j] = f2b(qv[j]);
                    }
                    *(f32x4*)(q + off) = qv;
                    *(u16x4*)(qb + off) = qbv;
                }
            }
        }
    }
}

// ---------------- host launch ----------------
extern "C" void kernel_launch(void* const* d_in, const int* in_sizes, int n_in,
                              void* d_out, int out_size, void* d_ws, size_t ws_size,
                              hipStream_t stream) {
    const float* table = (const float*)d_in[0];
    const float* logm  = (const float*)d_in[1];
    const float* W1    = (const float*)d_in[2];
    const float* b1    = (const float*)d_in[3];
    const float* W2    = (const float*)d_in[4];
    // d_in[5] = b2, unused by the force (only shifts the potential value)
    const int*   ids   = (const int*)d_in[6];

    float* q = (float*)d_out;                       // [BS, D]
    float* p = q + (size_t)BS_SZ * D_SZ;            // [BS, D]

    char* ws = (char*)d_ws;
    size_t o = 0;
    ushort_t* qb  = (ushort_t*)(ws + o); o += (size_t)BS_SZ * D_SZ * 2;   // 32 MB
    ushort_t* U   = (ushort_t*)(ws + o); o += (size_t)BS_SZ * H_SZ * 2;   // 128 MB
    ushort_t* W1b = (ushort_t*)(ws + o); o += (size_t)H_SZ * D_SZ * 2;    // 2 MB
    ushort_t* W1T = (ushort_t*)(ws + o); o += (size_t)D_SZ * H_SZ * 2;    // 2 MB
    float* inv_mass = (float*)(ws + o);  o += S_SZ * 4;
    float* mass     = (float*)(ws + o);  o += S_SZ * 4;

    prep_w1<<<(H_SZ * D_SZ) / 256, 256, 0, stream>>>(W1, W1b, W1T);
    prep_mass<<<(S_SZ + 255) / 256, 256, 0, stream>>>(logm, inv_mass, mass);
    embed_kernel<<<BS_SZ, 128, 0, stream>>>(table, ids, mass, q, p, qb);

    // 6 distinct force evals: j=0 -> +0.05*f(q0); j=1..4 -> +0.1*f(qj); j=5 -> +0.05*f(q5)
    for (int j = 0; j < 6; ++j) {
        // force1: A = W1b [2048 rows], B = qb [32768 rows], K=512 -> grid 8*128
        gemm8<512, 8, 0><<<1024, 512, 0, stream>>>(
            W1b, qb, b1, W2, U, nullptr, nullptr, nullptr, nullptr, nullptr, 0.f, 0);
        float coef = (j == 0 || j == 5) ? 0.05f : 0.1f;
        // force2: A = W1T [512 rows], B = U [32768 rows], K=2048 -> grid 2*128
        gemm8<2048, 2, 1><<<256, 512, 0, stream>>>(
            W1T, U, nullptr, nullptr, nullptr, ids, inv_mass, q, p, qb, coef, (j < 5) ? 1 : 0);
    }
}